// Round 10
// baseline (88.671 us; speedup 1.0000x reference)
//
#include <hip/hip_runtime.h>
#include <hip/hip_bf16.h>
#include <math.h>

#define B_ 4
#define T_ 1024
#define S_ 1024
#define H_ 1024
#define NH_ 16
#define DH_ 64
#define NEGV -4294967296.0f
#define EPS_ 1e-5f

typedef __attribute__((ext_vector_type(8))) short short8;       // 8 x bf16 bits (mfma A/B frag)
typedef __attribute__((ext_vector_type(8))) unsigned short ushort8;
typedef __attribute__((ext_vector_type(4))) unsigned short ushort4v;
typedef __attribute__((ext_vector_type(4))) unsigned int uint4v;
typedef __attribute__((ext_vector_type(4))) float f32x4;

__device__ __forceinline__ unsigned short f2bf(float x) {
    unsigned int u = __float_as_uint(x);
    u += 0x7FFF + ((u >> 16) & 1);          // round-to-nearest-even
    return (unsigned short)(u >> 16);
}

__device__ __forceinline__ float bf2f(unsigned short u) {
    return __uint_as_float(((unsigned int)u) << 16);
}

__device__ __forceinline__ unsigned int pack_bf16(float a, float b) {
    union { __hip_bfloat162 h; unsigned int u; } cv;
    cv.h = __float22bfloat162_rn(float2{a, b});   // a -> low16, b -> high16
    return cv.u;
}

__device__ __forceinline__ void gload16(const unsigned short* g, unsigned short* l) {
    __builtin_amdgcn_global_load_lds(
        (const __attribute__((address_space(1))) unsigned int*)g,
        (__attribute__((address_space(3))) unsigned int*)l,
        16, 0, 0);
}

#define VMCNT(n) asm volatile("s_waitcnt vmcnt(" #n ")" ::: "memory")
#define LGKM0()  { asm volatile("s_waitcnt lgkmcnt(0)" ::: "memory"); \
                   __builtin_amdgcn_sched_barrier(0); }

// ---------------------------------------------------------------------------
// Kernel 0: fp32 -> bf16 cast of {queries, keys, Wq, Wk, Wv} into workspace.
// ---------------------------------------------------------------------------
__global__ __launch_bounds__(256) void cast_bf16(
    const float* __restrict__ q, const float* __restrict__ k,
    const float* __restrict__ wq, const float* __restrict__ wk,
    const float* __restrict__ wv,
    unsigned short* __restrict__ dq, unsigned short* __restrict__ dk,
    unsigned short* __restrict__ dwq, unsigned short* __restrict__ dwk,
    unsigned short* __restrict__ dwv)
{
    const int seg = blockIdx.y;
    const float* src; unsigned short* dst; int n;
    switch (seg) {
        case 0:  src = q;  dst = dq;  n = B_*T_*H_; break;
        case 1:  src = k;  dst = dk;  n = B_*S_*H_; break;
        case 2:  src = wq; dst = dwq; n = H_*H_;    break;
        case 3:  src = wk; dst = dwk; n = H_*H_;    break;
        default: src = wv; dst = dwv; n = H_*H_;    break;
    }
    const int i = (blockIdx.x * 256 + threadIdx.x) * 8;
    if (i >= n) return;
    float4 a = *(const float4*)&src[i];
    float4 b = *(const float4*)&src[i + 4];
    ushort8 o;
    o[0] = f2bf(a.x); o[1] = f2bf(a.y); o[2] = f2bf(a.z); o[3] = f2bf(a.w);
    o[4] = f2bf(b.x); o[5] = f2bf(b.y); o[6] = f2bf(b.z); o[7] = f2bf(b.w);
    *(ushort8*)&dst[i] = o;
}

// ---------------------------------------------------------------------------
// Kernel 1 (R25): fused QKV projection — 256x256 tile, BK=64, 512 threads
// (8 waves 2Mx4N), restructured into the m201-style 8-PHASE schedule with
// counted vmcnt(6) (T3+T4).  stageA/stageB (half-tiles), readA/readB,
// mfmaQ (quadrants), LDS layout, swizzles and epilogue are VERBATIM from
// the proven Round-0 kernel; only the phase/sync structure changed.
// Per iteration (2 K-tiles kt=2i,2i+1; buf0=kt even @0, buf1 @32768):
//  p0 rdA0,rdB0->blo | stA1(kt+1)      | bar lgkm mfma<0,0> bar
//  p1 rdB1->bhi      | stA0(kt+2)      | bar lgkm mfma<0,1> bar
//  p2 rdA1           | stB0(kt+2)      | bar lgkm mfma<1,0> bar
//  p3                | stB1(kt+2)      | bar      mfma<1,1> VMCNT(6) bar
//  p4..p7: same on buf1, staging A1(kt+2), A0/B0/B1(kt+3), VMCNT(6)@p7
// Hazard ledger (audited): each half staged >=1 barrier-pair after its
// last-read phase; p7's vmcnt(6) leaves only {p5,p6,p7} outstanding ->
// buf0(kt+2) landed before next p0; p3's vmcnt(6) leaves {p1,p2,p3} ->
// buf1(kt+1) fully landed before p4.  Prologue: 7 halves + vmcnt(6).
// Tail (i=7): only p0's stage; VMCNT(0) at p3.  Accumulation order is
// bit-identical to the proven kernel.
// ---------------------------------------------------------------------------
template<int MH, int NHq>
__device__ __forceinline__ void mfmaQ(f32x4 (&acc)[8][4],
                                      const short8 (&afr)[4][2],
                                      const short8 (&bfr)[2][2])
{
    #pragma unroll
    for (int i2 = 0; i2 < 4; ++i2)
        #pragma unroll
        for (int j2 = 0; j2 < 2; ++j2)
            #pragma unroll
            for (int kc = 0; kc < 2; ++kc)
                acc[MH*4+i2][NHq*2+j2] = __builtin_amdgcn_mfma_f32_16x16x32_bf16(
                    afr[i2][kc], bfr[j2][kc], acc[MH*4+i2][NHq*2+j2], 0, 0, 0);
}

__global__ __launch_bounds__(512) void qkv_mfma(
    const unsigned short* __restrict__ Xq, const unsigned short* __restrict__ Xk,
    const unsigned short* __restrict__ Wq, const unsigned short* __restrict__ Wk,
    const unsigned short* __restrict__ Wv,
    const float* __restrict__ bq, const float* __restrict__ bk,
    const float* __restrict__ bv,
    unsigned short* __restrict__ Qo, unsigned short* __restrict__ Ko,
    unsigned short* __restrict__ Vo)
{
    const int bi = (blockIdx.x & 7) * 24 + (blockIdx.x >> 3);
    const int col_t = bi >> 4, row_t = bi & 15;
    const int which = col_t >> 2;                 // 0:Q 1:K 2:V
    const int colW = (col_t & 3) * 256;
    const int row0 = row_t * 256;

    const unsigned short* X = (which == 0) ? Xq : Xk;
    const unsigned short* Wm = (which == 0) ? Wq : (which == 1) ? Wk : Wv;
    const float* bias        = (which == 0) ? bq : (which == 1) ? bk : bv;
    unsigned short* Out      = (which == 0) ? Qo : (which == 1) ? Ko : Vo;

    __shared__ __align__(16) unsigned short S[67584];

    const int tid = threadIdx.x;
    const int wid = tid >> 6, lane = tid & 63, lo = lane & 15, hi = lane >> 4;
    const int wm = wid >> 2, wn = wid & 3;
    const int swr = (lo & 7) << 3;
    const int csw = ((tid & 7) << 3) ^ (((tid >> 3) & 7) << 3);

    auto stageA = [&](int mh, int kt) {           // one A half-tile: 2 gload16
        const int k0 = kt << 6;
        unsigned short* dst = &S[(kt & 1) * 32768 + mh * 8192 + wid * 512];
        #pragma unroll
        for (int u = 0; u < 2; ++u) {
            const int rowT = row0 + u * 128 + mh * 64 + (tid >> 3);
            gload16(&X[(size_t)rowT * H_ + k0 + csw], dst + u * 4096);
        }
    };
    auto stageB = [&](int nh, int kt) {           // one B half-tile: 2 gload16
        const int k0 = kt << 6;
        unsigned short* dst = &S[(kt & 1) * 32768 + 16384 + nh * 8192 + wid * 512];
        #pragma unroll
        for (int u = 0; u < 2; ++u) {
            const int pr = u * 64 + (tid >> 3);
            const int n  = (pr >> 5) * 64 + nh * 32 + (pr & 31);
            gload16(&Wm[(size_t)(colW + n) * H_ + k0 + csw], dst + u * 4096);
        }
    };

    short8 afr[4][2], blo[2][2], bhi[2][2];
    f32x4 acc[8][4] = {};

    auto readA = [&](int boff, int mh) {
        #pragma unroll
        for (int i2 = 0; i2 < 4; ++i2)
            #pragma unroll
            for (int kc = 0; kc < 2; ++kc)
                afr[i2][kc] = *(const short8*)
                    &S[boff + mh*8192 + (wm*64 + i2*16 + lo)*64 + ((kc*32 + hi*8) ^ swr)];
    };
    auto readB = [&](int boff, int nh, short8 (&bf)[2][2]) {
        #pragma unroll
        for (int j2 = 0; j2 < 2; ++j2)
            #pragma unroll
            for (int kc = 0; kc < 2; ++kc)
                bf[j2][kc] = *(const short8*)
                    &S[boff + 16384 + nh*8192 + (wn*32 + j2*16 + lo)*64 + ((kc*32 + hi*8) ^ swr)];
    };

    float bj[4];
    #pragma unroll
    for (int j = 0; j < 4; ++j)
        bj[j] = bias[colW + wn*64 + (j>>1)*32 + (j&1)*16 + lo];

    // prologue: buf0 {A0,B0,B1,A1} + buf1 {A0,B0,B1} = 14 loads
    stageA(0, 0); stageB(0, 0); stageB(1, 0); stageA(1, 0);
    stageA(0, 1); stageB(0, 1); stageB(1, 1);
    VMCNT(6);                       // buf0(0) landed; buf1's 3 halves in flight
    __builtin_amdgcn_s_barrier();

    for (int i = 0; i < 8; ++i) {
        const int kt = i * 2;
        const bool st = (i <= 6);
        // ---- p0: quadrant (0,0) of kt ----
        readA(0, 0);
        readB(0, 0, blo);
        stageA(1, kt + 1);                        // complete buf1 for this iter
        __builtin_amdgcn_s_barrier();
        LGKM0();
        __builtin_amdgcn_s_setprio(1); mfmaQ<0,0>(acc, afr, blo); __builtin_amdgcn_s_setprio(0);
        __builtin_amdgcn_s_barrier();
        // ---- p1: quadrant (0,1) ----
        readB(0, 1, bhi);
        if (st) stageA(0, kt + 2);
        __builtin_amdgcn_s_barrier();
        LGKM0();
        __builtin_amdgcn_s_setprio(1); mfmaQ<0,1>(acc, afr, bhi); __builtin_amdgcn_s_setprio(0);
        __builtin_amdgcn_s_barrier();
        // ---- p2: quadrant (1,0) ----
        readA(0, 1);
        if (st) stageB(0, kt + 2);
        __builtin_amdgcn_s_barrier();
        LGKM0();
        __builtin_amdgcn_s_setprio(1); mfmaQ<1,0>(acc, afr, blo); __builtin_amdgcn_s_setprio(0);
        __builtin_amdgcn_s_barrier();
        // ---- p3: quadrant (1,1) ----
        if (st) stageB(1, kt + 2);
        __builtin_amdgcn_s_barrier();
        __builtin_amdgcn_s_setprio(1); mfmaQ<1,1>(acc, afr, bhi); __builtin_amdgcn_s_setprio(0);
        if (st) { VMCNT(6); } else { VMCNT(0); }  // buf1(kt+1) fully landed
        __builtin_amdgcn_s_barrier();
        // ---- p4: quadrant (0,0) of kt+1 ----
        readA(32768, 0);
        readB(32768, 0, blo);
        if (st) stageA(1, kt + 2);
        __builtin_amdgcn_s_barrier();
        LGKM0();
        __builtin_amdgcn_s_setprio(1); mfmaQ<0,0>(acc, afr, blo); __builtin_amdgcn_s_setprio(0);
        __builtin_amdgcn_s_barrier();
        // ---- p5: quadrant (0,1) ----
        readB(32768, 1, bhi);
        if (st) stageA(0, kt + 3);
        __builtin_amdgcn_s_barrier();
        LGKM0();
        __builtin_amdgcn_s_setprio(1); mfmaQ<0,1>(acc, afr, bhi); __builtin_amdgcn_s_setprio(0);
        __builtin_amdgcn_s_barrier();
        // ---- p6: quadrant (1,0) ----
        readA(32768, 1);
        if (st) stageB(0, kt + 3);
        __builtin_amdgcn_s_barrier();
        LGKM0();
        __builtin_amdgcn_s_setprio(1); mfmaQ<1,0>(acc, afr, blo); __builtin_amdgcn_s_setprio(0);
        __builtin_amdgcn_s_barrier();
        // ---- p7: quadrant (1,1) ----
        if (st) stageB(1, kt + 3);
        __builtin_amdgcn_s_barrier();
        __builtin_amdgcn_s_setprio(1); mfmaQ<1,1>(acc, afr, bhi); __builtin_amdgcn_s_setprio(0);
        if (st) { VMCNT(6); }                     // buf0(kt+2) fully landed
        __builtin_amdgcn_s_barrier();
    }

    // ---- epilogue: bias + relu + bf16 via LDS retile, coalesced stores ----
    #pragma unroll
    for (int i = 0; i < 8; ++i) {
        const int er = wm*128 + (i>>2)*64 + (i&3)*16 + hi*4;
        #pragma unroll
        for (int j = 0; j < 4; ++j) {
            const int ec = wn*64 + (j>>1)*32 + (j&1)*16 + lo;
            #pragma unroll
            for (int r = 0; r < 4; ++r)
                S[(er + r) * 264 + ec] = f2bf(fmaxf(acc[i][j][r] + bj[j], 0.f));
        }
    }
    __syncthreads();
    #pragma unroll
    for (int u = 0; u < 16; ++u) {
        const int cid = u * 512 + tid;
        const int rr = cid >> 5, ch = cid & 31;
        ushort8 v = *(const ushort8*)&S[rr * 264 + ch * 8];
        *(ushort8*)&Out[(size_t)(row0 + rr) * H_ + colW + ch * 8] = v;
    }
}

// ---------------------------------------------------------------------------
// Kernel 1b: per-(b,h) PARTIAL column means of V (4 s-chunks -> 256 blocks)
// + per-b first-valid-key index (blocks 0..3).
// ---------------------------------------------------------------------------
__global__ __launch_bounds__(256) void vmean_prep(
    const unsigned short* __restrict__ V, const int* __restrict__ kmask,
    float* __restrict__ vmean_part, int* __restrict__ sfirst)
{
    const int bh = blockIdx.x >> 2, chunk = blockIdx.x & 3;
    const int b = bh >> 4, h = bh & 15;
    const int tid = threadIdx.x;
    const int d8 = tid & 7, sg = tid >> 3;     // 32 s-groups x 8-elem d-chunks

    __shared__ float red[32][68];
    __shared__ int sf_sh;
    if (tid == 0) sf_sh = S_;

    float acc[8] = {0,0,0,0,0,0,0,0};
    #pragma unroll
    for (int it = 0; it < 8; ++it) {
        const int s = chunk * 256 + sg + it * 32;
        ushort8 v = *(const ushort8*)&V[((size_t)b*S_ + s) * H_ + h*DH_ + d8*8];
        #pragma unroll
        for (int i = 0; i < 8; ++i) acc[i] += bf2f(v[i]);
    }
    #pragma unroll
    for (int i = 0; i < 8; ++i) red[sg][d8*8 + i] = acc[i];

    if (blockIdx.x < B_) {               // blocks 0..3: sfirst[b = blockIdx.x]
        int lf = S_;
        #pragma unroll
        for (int u = 0; u < 4; ++u) {
            const int s = tid + u * 256;
            if (kmask[blockIdx.x * S_ + s] != 0) lf = min(lf, s);
        }
        atomicMin(&sf_sh, lf);
    }
    __syncthreads();

    for (int str = 16; str >= 1; str >>= 1) {
        if (sg < str) {
            #pragma unroll
            for (int i = 0; i < 8; ++i)
                red[sg][d8*8 + i] += red[sg + str][d8*8 + i];
        }
        __syncthreads();
    }
    if (tid < 64) vmean_part[blockIdx.x * 64 + tid] = red[0][tid] * (1.f / 1024.f);
    if (blockIdx.x < B_ && tid == 0) sfirst[blockIdx.x] = sf_sh;
}

// ---------------------------------------------------------------------------
// Kernel 2 (R24, kept): MFMA flash attention, swapped-QK^T.  1024 blocks,
// one (b,h,qt) each, largest qt first; launch_bounds(256,3) -> no spill,
// 3 blocks/CU.  Proven R15 inner loop.
// ---------------------------------------------------------------------------
__global__ __launch_bounds__(256, 3) void attn_mfma(
    const unsigned short* __restrict__ Q, const unsigned short* __restrict__ K,
    const unsigned short* __restrict__ V, const int* __restrict__ kmask,
    const float* __restrict__ vmean_part, const int* __restrict__ sfirst,
    unsigned short* __restrict__ Ob)
{
    const int flat = blockIdx.x;
    const int qt = 15 - (flat >> 6);               // biggest first
    const int bh = (flat & 7) * 8 + ((flat >> 3) & 7);
    const int b = bh >> 4, h = bh & 15;

    const int tid = threadIdx.x;
    const int wid = tid >> 6, lane = tid & 63, hi = lane >> 4, lo = lane & 15;

    __shared__ unsigned short Ks[2][64][64];   // [buf][s][d], row-XOR swizzled
    __shared__ unsigned short Vt[2][64][64];   // [buf][d][perm(s)^swz]

    const int s_first = sfirst[b];

    // staging geometry (R13)
    const int srow = tid >> 2, d0k = (tid & 3) << 4, swk = (srow & 7) << 3;
    const int sp = tid & 31, dg = tid >> 5;            // V: s-pair, d-group
    const int s2 = sp * 2;
    const int ps = (s2 & 35) | ((s2 & 16) >> 2) | ((s2 & 12) << 1);  // perm(s2)

    ushort8 krA0, krA1, vrA0, vrA1; int kmA;
    ushort8 krB0, krB1, vrB0, vrB1; int kmB;

    auto stage_load = [&](int s0_, ushort8& k0, ushort8& k1,
                          ushort8& v0, ushort8& v1, int& kmr) {
        const unsigned short* kp = &K[((size_t)b*S_ + s0_ + srow) * H_ + h*DH_ + d0k];
        k0 = *(const ushort8*)kp;
        k1 = *(const ushort8*)(kp + 8);
        const unsigned short* vp = &V[((size_t)b*S_ + s0_ + s2) * H_ + h*DH_ + dg*8];
        v0 = *(const ushort8*)vp;
        v1 = *(const ushort8*)(vp + H_);
        kmr = kmask[b*S_ + s0_ + lane];
    };
    auto stage_write = [&](int pb, const ushort8& k0, const ushort8& k1,
                           const ushort8& v0, const ushort8& v1) {
        *(ushort8*)&Ks[pb][srow][d0k ^ swk]       = k0;
        *(ushort8*)&Ks[pb][srow][(d0k + 8) ^ swk] = k1;
        #pragma unroll
        for (int i = 0; i < 8; ++i) {
            const int d = dg*8 + i;
            const unsigned int pk = (unsigned int)(unsigned short)v0[i]
                                  | ((unsigned int)(unsigned short)v1[i] << 16);
            *(unsigned int*)&Vt[pb][d][ps ^ ((d & 7) << 3)] = pk;
        }
    };

    const int t0 = qt * 64;
    const int ntiles = qt + 1;                 // purely causal range
    const int tq = t0 + wid*16 + lo;           // q row this lane owns in P

    short8 qf0, qf1;
    {
        const unsigned short* qp =
            &Q[((size_t)b*T_ + t0 + wid*16 + lo) * H_ + h*DH_ + hi*8];
        qf0 = *(const short8*)qp;
        qf1 = *(const short8*)(qp + 32);
    }

    float m = -INFINITY, l = 0.f;
    f32x4 oacc[4] = {{0,0,0,0},{0,0,0,0},{0,0,0,0},{0,0,0,0}};

    auto compute = [&](int pb, int s0, int kmr) {
        const unsigned long long kmb = __ballot(kmr != 0);
        f32x4 sc[4] = {{0,0,0,0},{0,0,0,0},{0,0,0,0},{0,0,0,0}};
        const int swq = (lo & 7) << 3;
        __builtin_amdgcn_s_setprio(1);
        #pragma unroll
        for (int n = 0; n < 4; ++n) {
            short8 kfa = *(const short8*)&Ks[pb][n*16 + lo][(hi*8) ^ swq];
            sc[n] = __builtin_amdgcn_mfma_f32_16x16x32_bf16(kfa, qf0, sc[n], 0, 0, 0);
            short8 kfb = *(const short8*)&Ks[pb][n*16 + lo][(32 + hi*8) ^ swq];
            sc[n] = __builtin_amdgcn_mfma_f32_16x16x32_bf16(kfb, qf1, sc[n], 0, 0, 0);
        }
        __builtin_amdgcn_s_setprio(0);
        float p[4][4];
        float rm = -INFINITY;
        #pragma unroll
        for (int n = 0; n < 4; ++n)
            #pragma unroll
            for (int r = 0; r < 4; ++r) {
                const int sl = n*16 + hi*4 + r;
                const bool msk = !((kmb >> sl) & 1ull) || (s0 + sl > tq);
                const float v = sc[n][r] * 0.03125f;
                p[n][r] = msk ? NEGV : v;
                rm = fmaxf(rm, p[n][r]);
            }
        rm = fmaxf(rm, __shfl_xor(rm, 16));
        rm = fmaxf(rm, __shfl_xor(rm, 32));
        if (__any(rm > m + 8.f)) {             // T13 defer-max
            const float mn  = fmaxf(m, rm);
            const float scl = __expf(m - mn);
            m = mn;
            l *= scl;
            #pragma unroll
            for (int r = 0; r < 4; ++r) {
                const float os = __shfl(scl, hi*4 + r);
                oacc[0][r] *= os; oacc[1][r] *= os;
                oacc[2][r] *= os; oacc[3][r] *= os;
            }
        }
        float ts = 0.f;
        #pragma unroll
        for (int n = 0; n < 4; ++n)
            #pragma unroll
            for (int r = 0; r < 4; ++r) {
                p[n][r] = __expf(p[n][r] - m);
                ts += p[n][r];
            }
        ts += __shfl_xor(ts, 16);
        ts += __shfl_xor(ts, 32);
        l += ts;
        unsigned int pk0[4], pk1[4];
        #pragma unroll
        for (int n = 0; n < 4; ++n) {
            pk0[n] = pack_bf16(p[n][0], p[n][1]);
            pk1[n] = pack_bf16(p[n][2], p[n][3]);
        }
        __builtin_amdgcn_s_setprio(1);
        #pragma unroll
        for (int cch = 0; cch < 2; ++cch) {
            uint4v u;
            u.x = pk0[2*cch];   u.y = pk1[2*cch];
            u.z = pk0[2*cch+1]; u.w = pk1[2*cch+1];
            const short8 pf = __builtin_bit_cast(short8, u);
            #pragma unroll
            for (int n2 = 0; n2 < 4; ++n2) {
                const int d = n2*16 + lo;
                const short8 vf =
                    *(const short8*)&Vt[pb][d][(cch*32 + hi*8) ^ ((d & 7) << 3)];
                oacc[n2] = __builtin_amdgcn_mfma_f32_16x16x32_bf16(pf, vf, oacc[n2], 0, 0, 0);
            }
        }
        __builtin_amdgcn_s_setprio(0);
    };

    stage_load(0, krA0, krA1, vrA0, vrA1, kmA);
    int t = 0;
    for (;;) {
        stage_write(0, krA0, krA1, vrA0, vrA1);
        if (t + 1 < ntiles) stage_load((t+1) << 6, krB0, krB1, vrB0, vrB1, kmB);
        __syncthreads();                // single barrier per tile
        compute(0, t << 6, kmA);
        if (++t >= ntiles) break;

        stage_write(1, krB0, krB1, vrB0, vrB1);
        if (t + 1 < ntiles) stage_load((t+1) << 6, krA0, krA1, vrA0, vrA1, kmA);
        __syncthreads();
        compute(1, t << 6, kmB);
        if (++t >= ntiles) break;
    }

    const float inv = 1.0f / l;
    #pragma unroll
    for (int r = 0; r < 4; ++r) {
        const float ir = __shfl(inv, hi*4 + r);
        const int trow = t0 + wid*16 + hi*4 + r;
        unsigned short* dst = &Ob[((size_t)b*T_ + trow) * H_ + h*DH_ + lo];
        if (trow < s_first) {           // all-NEG row: uniform softmax = mean(V)
            #pragma unroll
            for (int g = 0; g < 4; ++g) {
                float vm = vmean_part[(bh*4 + 0)*64 + lo + g*16]
                         + vmean_part[(bh*4 + 1)*64 + lo + g*16]
                         + vmean_part[(bh*4 + 2)*64 + lo + g*16]
                         + vmean_part[(bh*4 + 3)*64 + lo + g*16];
                dst[g*16] = f2bf(vm);
            }
        } else {
            dst[0]  = f2bf(oacc[0][r] * ir);
            dst[16] = f2bf(oacc[1][r] * ir);
            dst[32] = f2bf(oacc[2][r] * ir);
            dst[48] = f2bf(oacc[3][r] * ir);
        }
    }
}

// ---------------------------------------------------------------------------
// Kernel 3: residual + queries_mask + LayerNorm.  Reads bf16 attn-out (Ob)
// + fp32 queries, writes final fp32 Out.
// ---------------------------------------------------------------------------
__global__ __launch_bounds__(256) void ln_kernel(
    const unsigned short* __restrict__ Ob, float* __restrict__ Out,
    const float* __restrict__ queries, const int* __restrict__ qmask,
    const float* __restrict__ gamma, const float* __restrict__ beta)
{
    const int row = blockIdx.x;
    const int tid = threadIdx.x;
    const float qm = (float)qmask[row];

    ushort4v a4 = *(const ushort4v*)&Ob[(size_t)row * H_ + tid*4];
    float4 q4 = *(const float4*)&queries[(size_t)row * H_ + tid*4];
    float x0 = bf2f(a4.x) * qm + q4.x;
    float x1 = bf2f(a4.y) * qm + q4.y;
    float x2 = bf2f(a4.z) * qm + q4.z;
    float x3 = bf2f(a4.w) * qm + q4.w;

    float sum = x0 + x1 + x2 + x3;
    float sq  = x0*x0 + x1*x1 + x2*x2 + x3*x3;
    #pragma unroll
    for (int off = 32; off >= 1; off >>= 1) {
        sum += __shfl_down(sum, off);
        sq  += __shfl_down(sq,  off);
    }
    __shared__ float rs[4], rq[4];
    const int wid = tid >> 6, lane = tid & 63;
    if (lane == 0) { rs[wid] = sum; rq[wid] = sq; }
    __syncthreads();
    const float tot  = rs[0] + rs[1] + rs[2] + rs[3];
    const float totq = rq[0] + rq[1] + rq[2] + rq[3];
    const float mean = tot * (1.f / H_);
    const float var  = totq * (1.f / H_) - mean * mean;
    const float rstd = rsqrtf(var + EPS_);

    float4 g4 = *(const float4*)&gamma[tid*4];
    float4 b4 = *(const float4*)&beta[tid*4];
    float4 y;
    y.x = (x0 - mean) * rstd * g4.x + b4.x;
    y.y = (x1 - mean) * rstd * g4.y + b4.y;
    y.z = (x2 - mean) * rstd * g4.z + b4.z;
    y.w = (x3 - mean) * rstd * g4.w + b4.w;
    *(float4*)&Out[(size_t)row * H_ + tid*4] = y;
}

// ---------------------------------------------------------------------------
extern "C" void kernel_launch(void* const* d_in, const int* in_sizes, int n_in,
                              void* d_out, int out_size, void* d_ws, size_t ws_size,
                              hipStream_t stream)
{
    const float* queries = (const float*)d_in[0];
    const int*   qmask   = (const int*)  d_in[1];
    const float* keys    = (const float*)d_in[2];
    const int*   kmask   = (const int*)  d_in[3];
    const float* Wq      = (const float*)d_in[4];
    const float* bq      = (const float*)d_in[5];
    const float* Wk      = (const float*)d_in[6];
    const float* bk      = (const float*)d_in[7];
    const float* Wv      = (const float*)d_in[8];
    const float* bv      = (const float*)d_in[9];
    const float* gamma   = (const float*)d_in[10];
    const float* beta    = (const float*)d_in[11];
    float* out = (float*)d_out;

    unsigned short* Xqb = (unsigned short*)d_ws;
    unsigned short* Xkb = Xqb + (size_t)B_*T_*H_;
    unsigned short* Wqb = Xkb + (size_t)B_*S_*H_;
    unsigned short* Wkb = Wqb + (size_t)H_*H_;
    unsigned short* Wvb = Wkb + (size_t)H_*H_;
    unsigned short* Qb  = Wvb + (size_t)H_*H_;
    unsigned short* Kb  = Qb  + (size_t)B_*T_*H_;
    unsigned short* Vb  = Kb  + (size_t)B_*S_*H_;
    float* vmeanF = (float*)Xqb;          // dead-after-GEMM region (Xqb)
    int*   sfirstI = (int*)(vmeanF + 256*64);
    unsigned short* Ob = Xkb;             // dead-after-GEMM region (Xkb), 8 MB

    dim3 gc((B_*T_*H_/8 + 255)/256, 5, 1);
    cast_bf16<<<gc, 256, 0, stream>>>(queries, keys, Wq, Wk, Wv,
                                      Xqb, Xkb, Wqb, Wkb, Wvb);

    qkv_mfma<<<192, 512, 0, stream>>>(Xqb, Xkb, Wqb, Wkb, Wvb,
                                      bq, bk, bv, Qb, Kb, Vb);

    vmean_prep<<<256, 256, 0, stream>>>(Vb, kmask, vmeanF, sfirstI);

    attn_mfma<<<1024, 256, 0, stream>>>(Qb, Kb, Vb, kmask, vmeanF, sfirstI, Ob);

    ln_kernel<<<B_*T_, 256, 0, stream>>>(Ob, out, queries, qmask, gamma, beta);
}

// Round 11
// 86.418 us; speedup vs baseline: 1.0261x; 1.0261x over previous
//
#include <hip/hip_runtime.h>
#include <hip/hip_bf16.h>
#include <math.h>

#define B_ 4
#define T_ 1024
#define S_ 1024
#define H_ 1024
#define NH_ 16
#define DH_ 64
#define NEGV -4294967296.0f
#define EPS_ 1e-5f

typedef __attribute__((ext_vector_type(8))) short short8;       // 8 x bf16 bits (mfma A/B frag)
typedef __attribute__((ext_vector_type(8))) unsigned short ushort8;
typedef __attribute__((ext_vector_type(4))) unsigned short ushort4v;
typedef __attribute__((ext_vector_type(4))) unsigned int uint4v;
typedef __attribute__((ext_vector_type(4))) float f32x4;

__device__ __forceinline__ unsigned short f2bf(float x) {
    unsigned int u = __float_as_uint(x);
    u += 0x7FFF + ((u >> 16) & 1);          // round-to-nearest-even
    return (unsigned short)(u >> 16);
}

__device__ __forceinline__ float bf2f(unsigned short u) {
    return __uint_as_float(((unsigned int)u) << 16);
}

__device__ __forceinline__ unsigned int pack_bf16(float a, float b) {
    union { __hip_bfloat162 h; unsigned int u; } cv;
    cv.h = __float22bfloat162_rn(float2{a, b});   // a -> low16, b -> high16
    return cv.u;
}

__device__ __forceinline__ void gload16(const unsigned short* g, unsigned short* l) {
    __builtin_amdgcn_global_load_lds(
        (const __attribute__((address_space(1))) unsigned int*)g,
        (__attribute__((address_space(3))) unsigned int*)l,
        16, 0, 0);
}

#define VMCNT(n) asm volatile("s_waitcnt vmcnt(" #n ")" ::: "memory")
#define LGKM0()  { asm volatile("s_waitcnt lgkmcnt(0)" ::: "memory"); \
                   __builtin_amdgcn_sched_barrier(0); }

// ---------------------------------------------------------------------------
// Kernel 0: fp32 -> bf16 cast of {queries, keys, Wq, Wk, Wv} into workspace.
// ---------------------------------------------------------------------------
__global__ __launch_bounds__(256) void cast_bf16(
    const float* __restrict__ q, const float* __restrict__ k,
    const float* __restrict__ wq, const float* __restrict__ wk,
    const float* __restrict__ wv,
    unsigned short* __restrict__ dq, unsigned short* __restrict__ dk,
    unsigned short* __restrict__ dwq, unsigned short* __restrict__ dwk,
    unsigned short* __restrict__ dwv)
{
    const int seg = blockIdx.y;
    const float* src; unsigned short* dst; int n;
    switch (seg) {
        case 0:  src = q;  dst = dq;  n = B_*T_*H_; break;
        case 1:  src = k;  dst = dk;  n = B_*S_*H_; break;
        case 2:  src = wq; dst = dwq; n = H_*H_;    break;
        case 3:  src = wk; dst = dwk; n = H_*H_;    break;
        default: src = wv; dst = dwv; n = H_*H_;    break;
    }
    const int i = (blockIdx.x * 256 + threadIdx.x) * 8;
    if (i >= n) return;
    float4 a = *(const float4*)&src[i];
    float4 b = *(const float4*)&src[i + 4];
    ushort8 o;
    o[0] = f2bf(a.x); o[1] = f2bf(a.y); o[2] = f2bf(a.z); o[3] = f2bf(a.w);
    o[4] = f2bf(b.x); o[5] = f2bf(b.y); o[6] = f2bf(b.z); o[7] = f2bf(b.w);
    *(ushort8*)&dst[i] = o;
}

// ---------------------------------------------------------------------------
// Kernel 1: fused QKV projection (proven R18 form; R25's 8-phase 256^2 was
// neutral -> reverted, qkv closed at ~37us).  128x128 tile, BK=64, 512
// threads (8 waves 2Mx4N, acc[4][2]).  Grid 768 = 3*256, LDS 64KB ->
// 2 blocks/CU.  Race-free schedule per iter:
//   {12 ds_read -> lgkmcnt(0) -> barrier -> stage(it+2) -> 16 MFMA ->
//    vmcnt(4) -> barrier}
// ---------------------------------------------------------------------------
__global__ __launch_bounds__(512, 4) void qkv_mfma(
    const unsigned short* __restrict__ Xq, const unsigned short* __restrict__ Xk,
    const unsigned short* __restrict__ Wq, const unsigned short* __restrict__ Wk,
    const unsigned short* __restrict__ Wv,
    const float* __restrict__ bq, const float* __restrict__ bk,
    const float* __restrict__ bv,
    unsigned short* __restrict__ Qo, unsigned short* __restrict__ Ko,
    unsigned short* __restrict__ Vo)
{
    const int bi = (blockIdx.x & 7) * 96 + (blockIdx.x >> 3);
    const int col_t = bi >> 5, row_t = bi & 31;
    const int which = col_t >> 3;                 // 0:Q 1:K 2:V
    const int colW = (col_t & 7) * 128;
    const int row0 = row_t * 128;

    const unsigned short* X = (which == 0) ? Xq : Xk;
    const unsigned short* Wm = (which == 0) ? Wq : (which == 1) ? Wk : Wv;
    const float* bias        = (which == 0) ? bq : (which == 1) ? bk : bv;
    unsigned short* Out      = (which == 0) ? Qo : (which == 1) ? Ko : Vo;

    __shared__ __align__(16) unsigned short S[32768];

    const int tid = threadIdx.x;
    const int wid = tid >> 6, lane = tid & 63, lo = lane & 15, hi = lane >> 4;
    const int wm = wid >> 2, wn = wid & 3;        // 2M x 4N wave grid
    const int swr = (lo & 7) << 3;
    const int csw = ((tid & 7) << 3) ^ (((tid >> 3) & 7) << 3);

    auto stageA = [&](int kt) {
        const int k0 = kt << 6;
        unsigned short* dst = &S[(kt & 1) * 16384 + wid * 512];
        #pragma unroll
        for (int u = 0; u < 2; ++u) {
            const int rowT = row0 + u * 64 + (tid >> 3);
            gload16(&X[(size_t)rowT * H_ + k0 + csw], dst + u * 4096);
        }
    };
    auto stageB = [&](int kt) {
        const int k0 = kt << 6;
        unsigned short* dst = &S[(kt & 1) * 16384 + 8192 + wid * 512];
        #pragma unroll
        for (int u = 0; u < 2; ++u) {
            const int n = u * 64 + (tid >> 3);
            gload16(&Wm[(size_t)(colW + n) * H_ + k0 + csw], dst + u * 4096);
        }
    };

    short8 afr[4][2], bfr[2][2];
    f32x4 acc[4][2] = {};

    auto readA = [&](int boff) {
        #pragma unroll
        for (int i2 = 0; i2 < 4; ++i2)
            #pragma unroll
            for (int kc = 0; kc < 2; ++kc)
                afr[i2][kc] = *(const short8*)
                    &S[boff + (wm*64 + i2*16 + lo)*64 + ((kc*32 + hi*8) ^ swr)];
    };
    auto readB = [&](int boff) {
        #pragma unroll
        for (int j2 = 0; j2 < 2; ++j2)
            #pragma unroll
            for (int kc = 0; kc < 2; ++kc)
                bfr[j2][kc] = *(const short8*)
                    &S[boff + 8192 + (wn*32 + j2*16 + lo)*64 + ((kc*32 + hi*8) ^ swr)];
    };

    float bj[2];
    #pragma unroll
    for (int j2 = 0; j2 < 2; ++j2)
        bj[j2] = bias[colW + wn*32 + j2*16 + lo];

    stageA(0); stageB(0); stageA(1); stageB(1);
    VMCNT(4);
    __builtin_amdgcn_s_barrier();

    for (int it = 0; it < 16; ++it) {
        const int boff = (it & 1) * 16384;
        readA(boff);
        readB(boff);
        LGKM0();
        __builtin_amdgcn_s_barrier();
        if (it <= 13) { stageA(it + 2); stageB(it + 2); }
        __builtin_amdgcn_s_setprio(1);
        #pragma unroll
        for (int i2 = 0; i2 < 4; ++i2)
            #pragma unroll
            for (int j2 = 0; j2 < 2; ++j2)
                #pragma unroll
                for (int kc = 0; kc < 2; ++kc)
                    acc[i2][j2] = __builtin_amdgcn_mfma_f32_16x16x32_bf16(
                        afr[i2][kc], bfr[j2][kc], acc[i2][j2], 0, 0, 0);
        __builtin_amdgcn_s_setprio(0);
        if (it < 14) { VMCNT(4); } else { VMCNT(0); }
        __builtin_amdgcn_s_barrier();
    }

    #pragma unroll
    for (int i2 = 0; i2 < 4; ++i2) {
        const int er = wm*64 + i2*16 + hi*4;
        #pragma unroll
        for (int j2 = 0; j2 < 2; ++j2) {
            const int ec = wn*32 + j2*16 + lo;
            #pragma unroll
            for (int r = 0; r < 4; ++r)
                S[(er + r) * 136 + ec] = f2bf(fmaxf(acc[i2][j2][r] + bj[j2], 0.f));
        }
    }
    __syncthreads();
    #pragma unroll
    for (int u = 0; u < 4; ++u) {
        const int cid = u * 512 + tid;
        const int rr = cid >> 4, ch = cid & 15;
        ushort8 v = *(const ushort8*)&S[rr * 136 + ch * 8];
        *(ushort8*)&Out[(size_t)(row0 + rr) * H_ + colW + ch * 8] = v;
    }
}

// ---------------------------------------------------------------------------
// Kernel 1b: per-(b,h) PARTIAL column means of V (4 s-chunks -> 256 blocks)
// + per-b first-valid-key index (blocks 0..3).
// ---------------------------------------------------------------------------
__global__ __launch_bounds__(256) void vmean_prep(
    const unsigned short* __restrict__ V, const int* __restrict__ kmask,
    float* __restrict__ vmean_part, int* __restrict__ sfirst)
{
    const int bh = blockIdx.x >> 2, chunk = blockIdx.x & 3;
    const int b = bh >> 4, h = bh & 15;
    const int tid = threadIdx.x;
    const int d8 = tid & 7, sg = tid >> 3;     // 32 s-groups x 8-elem d-chunks

    __shared__ float red[32][68];
    __shared__ int sf_sh;
    if (tid == 0) sf_sh = S_;

    float acc[8] = {0,0,0,0,0,0,0,0};
    #pragma unroll
    for (int it = 0; it < 8; ++it) {
        const int s = chunk * 256 + sg + it * 32;
        ushort8 v = *(const ushort8*)&V[((size_t)b*S_ + s) * H_ + h*DH_ + d8*8];
        #pragma unroll
        for (int i = 0; i < 8; ++i) acc[i] += bf2f(v[i]);
    }
    #pragma unroll
    for (int i = 0; i < 8; ++i) red[sg][d8*8 + i] = acc[i];

    if (blockIdx.x < B_) {               // blocks 0..3: sfirst[b = blockIdx.x]
        int lf = S_;
        #pragma unroll
        for (int u = 0; u < 4; ++u) {
            const int s = tid + u * 256;
            if (kmask[blockIdx.x * S_ + s] != 0) lf = min(lf, s);
        }
        atomicMin(&sf_sh, lf);
    }
    __syncthreads();

    for (int str = 16; str >= 1; str >>= 1) {
        if (sg < str) {
            #pragma unroll
            for (int i = 0; i < 8; ++i)
                red[sg][d8*8 + i] += red[sg + str][d8*8 + i];
        }
        __syncthreads();
    }
    if (tid < 64) vmean_part[blockIdx.x * 64 + tid] = red[0][tid] * (1.f / 1024.f);
    if (blockIdx.x < B_ && tid == 0) sfirst[blockIdx.x] = sf_sh;
}

// ---------------------------------------------------------------------------
// Kernel 2 (R26): MFMA flash attention, swapped-QK^T.  1024 blocks, one
// (b,h,qt) each, largest qt first (R24 decode kept).
// Register trims to reach 4 blocks/CU SPILL-FREE (R23 spilled at (256,4)
// with ~150 live regs; R24 ran clean at (256,3) with ~31us):
//  (1) SINGLE staging regset (-16): kr/vr are dead after stage_write (the
//      ds_write reads them at issue), so stage_load(t+1) reuses the same
//      registers; the kmask ballot is hoisted BEFORE the reload (SGPR).
//  (2) p[4][4] merged into sc[4] (-16): mask/scale/exp in place, same math.
// Barrier-safety unchanged: compute(t-2) on buf[t&1] completes before
// barrier(t-1), which precedes any wave's stage_write(t).
// Spill tripwire: WRITE_SIZE must stay ~8.4 MB.
// ---------------------------------------------------------------------------
__global__ __launch_bounds__(256, 4) void attn_mfma(
    const unsigned short* __restrict__ Q, const unsigned short* __restrict__ K,
    const unsigned short* __restrict__ V, const int* __restrict__ kmask,
    const float* __restrict__ vmean_part, const int* __restrict__ sfirst,
    unsigned short* __restrict__ Ob)
{
    const int flat = blockIdx.x;
    const int qt = 15 - (flat >> 6);               // biggest first
    const int bh = (flat & 7) * 8 + ((flat >> 3) & 7);
    const int b = bh >> 4, h = bh & 15;

    const int tid = threadIdx.x;
    const int wid = tid >> 6, lane = tid & 63, hi = lane >> 4, lo = lane & 15;

    __shared__ unsigned short Ks[2][64][64];   // [buf][s][d], row-XOR swizzled
    __shared__ unsigned short Vt[2][64][64];   // [buf][d][perm(s)^swz]

    const int s_first = sfirst[b];

    // staging geometry (R13)
    const int srow = tid >> 2, d0k = (tid & 3) << 4, swk = (srow & 7) << 3;
    const int sp = tid & 31, dg = tid >> 5;            // V: s-pair, d-group
    const int s2 = sp * 2;
    const int ps = (s2 & 35) | ((s2 & 16) >> 2) | ((s2 & 12) << 1);  // perm(s2)

    ushort8 kr0, kr1, vr0, vr1; int kmr;           // SINGLE staging regset

    auto stage_load = [&](int s0_) {
        const unsigned short* kp = &K[((size_t)b*S_ + s0_ + srow) * H_ + h*DH_ + d0k];
        kr0 = *(const ushort8*)kp;
        kr1 = *(const ushort8*)(kp + 8);
        const unsigned short* vp = &V[((size_t)b*S_ + s0_ + s2) * H_ + h*DH_ + dg*8];
        vr0 = *(const ushort8*)vp;
        vr1 = *(const ushort8*)(vp + H_);
        kmr = kmask[b*S_ + s0_ + lane];
    };
    auto stage_write = [&](int pb) {
        *(ushort8*)&Ks[pb][srow][d0k ^ swk]       = kr0;
        *(ushort8*)&Ks[pb][srow][(d0k + 8) ^ swk] = kr1;
        #pragma unroll
        for (int i = 0; i < 8; ++i) {
            const int d = dg*8 + i;
            const unsigned int pk = (unsigned int)(unsigned short)vr0[i]
                                  | ((unsigned int)(unsigned short)vr1[i] << 16);
            *(unsigned int*)&Vt[pb][d][ps ^ ((d & 7) << 3)] = pk;
        }
    };

    const int t0 = qt * 64;
    const int ntiles = qt + 1;                 // purely causal range
    const int tq = t0 + wid*16 + lo;           // q row this lane owns in P

    short8 qf0, qf1;
    {
        const unsigned short* qp =
            &Q[((size_t)b*T_ + t0 + wid*16 + lo) * H_ + h*DH_ + hi*8];
        qf0 = *(const short8*)qp;
        qf1 = *(const short8*)(qp + 32);
    }

    float m = -INFINITY, l = 0.f;
    f32x4 oacc[4] = {{0,0,0,0},{0,0,0,0},{0,0,0,0},{0,0,0,0}};

    auto compute = [&](int pb, int s0, unsigned long long kmb) {
        f32x4 sc[4] = {{0,0,0,0},{0,0,0,0},{0,0,0,0},{0,0,0,0}};
        const int swq = (lo & 7) << 3;
        __builtin_amdgcn_s_setprio(1);
        #pragma unroll
        for (int n = 0; n < 4; ++n) {
            short8 kfa = *(const short8*)&Ks[pb][n*16 + lo][(hi*8) ^ swq];
            sc[n] = __builtin_amdgcn_mfma_f32_16x16x32_bf16(kfa, qf0, sc[n], 0, 0, 0);
            short8 kfb = *(const short8*)&Ks[pb][n*16 + lo][(32 + hi*8) ^ swq];
            sc[n] = __builtin_amdgcn_mfma_f32_16x16x32_bf16(kfb, qf1, sc[n], 0, 0, 0);
        }
        __builtin_amdgcn_s_setprio(0);
        // mask + scale IN PLACE (sc doubles as p; same FP sequence as before)
        float rm = -INFINITY;
        #pragma unroll
        for (int n = 0; n < 4; ++n)
            #pragma unroll
            for (int r = 0; r < 4; ++r) {
                const int sl = n*16 + hi*4 + r;
                const bool msk = !((kmb >> sl) & 1ull) || (s0 + sl > tq);
                sc[n][r] = msk ? NEGV : sc[n][r] * 0.03125f;
                rm = fmaxf(rm, sc[n][r]);
            }
        rm = fmaxf(rm, __shfl_xor(rm, 16));
        rm = fmaxf(rm, __shfl_xor(rm, 32));
        if (__any(rm > m + 8.f)) {             // T13 defer-max
            const float mn  = fmaxf(m, rm);
            const float scl = __expf(m - mn);
            m = mn;
            l *= scl;
            #pragma unroll
            for (int r = 0; r < 4; ++r) {
                const float os = __shfl(scl, hi*4 + r);
                oacc[0][r] *= os; oacc[1][r] *= os;
                oacc[2][r] *= os; oacc[3][r] *= os;
            }
        }
        float ts = 0.f;
        #pragma unroll
        for (int n = 0; n < 4; ++n)
            #pragma unroll
            for (int r = 0; r < 4; ++r) {
                sc[n][r] = __expf(sc[n][r] - m);
                ts += sc[n][r];
            }
        ts += __shfl_xor(ts, 16);
        ts += __shfl_xor(ts, 32);
        l += ts;
        unsigned int pk0[4], pk1[4];
        #pragma unroll
        for (int n = 0; n < 4; ++n) {
            pk0[n] = pack_bf16(sc[n][0], sc[n][1]);
            pk1[n] = pack_bf16(sc[n][2], sc[n][3]);
        }
        __builtin_amdgcn_s_setprio(1);
        #pragma unroll
        for (int cch = 0; cch < 2; ++cch) {
            uint4v u;
            u.x = pk0[2*cch];   u.y = pk1[2*cch];
            u.z = pk0[2*cch+1]; u.w = pk1[2*cch+1];
            const short8 pf = __builtin_bit_cast(short8, u);
            #pragma unroll
            for (int n2 = 0; n2 < 4; ++n2) {
                const int d = n2*16 + lo;
                const short8 vf =
                    *(const short8*)&Vt[pb][d][(cch*32 + hi*8) ^ ((d & 7) << 3)];
                oacc[n2] = __builtin_amdgcn_mfma_f32_16x16x32_bf16(pf, vf, oacc[n2], 0, 0, 0);
            }
        }
        __builtin_amdgcn_s_setprio(0);
    };

    stage_load(0);
    for (int t = 0; t < ntiles; ++t) {
        stage_write(t & 1);
        const unsigned long long kmb = __ballot(kmr != 0);  // SGPR, pre-reload
        if (t + 1 < ntiles) stage_load((t + 1) << 6);       // reuse regset
        __syncthreads();                // single barrier per tile
        compute(t & 1, t << 6, kmb);
    }

    const float inv = 1.0f / l;
    #pragma unroll
    for (int r = 0; r < 4; ++r) {
        const float ir = __shfl(inv, hi*4 + r);
        const int trow = t0 + wid*16 + hi*4 + r;
        unsigned short* dst = &Ob[((size_t)b*T_ + trow) * H_ + h*DH_ + lo];
        if (trow < s_first) {           // all-NEG row: uniform softmax = mean(V)
            #pragma unroll
            for (int g = 0; g < 4; ++g) {
                float vm = vmean_part[(bh*4 + 0)*64 + lo + g*16]
                         + vmean_part[(bh*4 + 1)*64 + lo + g*16]
                         + vmean_part[(bh*4 + 2)*64 + lo + g*16]
                         + vmean_part[(bh*4 + 3)*64 + lo + g*16];
                dst[g*16] = f2bf(vm);
            }
        } else {
            dst[0]  = f2bf(oacc[0][r] * ir);
            dst[16] = f2bf(oacc[1][r] * ir);
            dst[32] = f2bf(oacc[2][r] * ir);
            dst[48] = f2bf(oacc[3][r] * ir);
        }
    }
}

// ---------------------------------------------------------------------------
// Kernel 3: residual + queries_mask + LayerNorm.  Reads bf16 attn-out (Ob)
// + fp32 queries, writes final fp32 Out.
// ---------------------------------------------------------------------------
__global__ __launch_bounds__(256) void ln_kernel(
    const unsigned short* __restrict__ Ob, float* __restrict__ Out,
    const float* __restrict__ queries, const int* __restrict__ qmask,
    const float* __restrict__ gamma, const float* __restrict__ beta)
{
    const int row = blockIdx.x;
    const int tid = threadIdx.x;
    const float qm = (float)qmask[row];

    ushort4v a4 = *(const ushort4v*)&Ob[(size_t)row * H_ + tid*4];
    float4 q4 = *(const float4*)&queries[(size_t)row * H_ + tid*4];
    float x0 = bf2f(a4.x) * qm + q4.x;
    float x1 = bf2f(a4.y) * qm + q4.y;
    float x2 = bf2f(a4.z) * qm + q4.z;
    float x3 = bf2f(a4.w) * qm + q4.w;

    float sum = x0 + x1 + x2 + x3;
    float sq  = x0*x0 + x1*x1 + x2*x2 + x3*x3;
    #pragma unroll
    for (int off = 32; off >= 1; off >>= 1) {
        sum += __shfl_down(sum, off);
        sq  += __shfl_down(sq,  off);
    }
    __shared__ float rs[4], rq[4];
    const int wid = tid >> 6, lane = tid & 63;
    if (lane == 0) { rs[wid] = sum; rq[wid] = sq; }
    __syncthreads();
    const float tot  = rs[0] + rs[1] + rs[2] + rs[3];
    const float totq = rq[0] + rq[1] + rq[2] + rq[3];
    const float mean = tot * (1.f / H_);
    const float var  = totq * (1.f / H_) - mean * mean;
    const float rstd = rsqrtf(var + EPS_);

    float4 g4 = *(const float4*)&gamma[tid*4];
    float4 b4 = *(const float4*)&beta[tid*4];
    float4 y;
    y.x = (x0 - mean) * rstd * g4.x + b4.x;
    y.y = (x1 - mean) * rstd * g4.y + b4.y;
    y.z = (x2 - mean) * rstd * g4.z + b4.z;
    y.w = (x3 - mean) * rstd * g4.w + b4.w;
    *(float4*)&Out[(size_t)row * H_ + tid*4] = y;
}

// ---------------------------------------------------------------------------
extern "C" void kernel_launch(void* const* d_in, const int* in_sizes, int n_in,
                              void* d_out, int out_size, void* d_ws, size_t ws_size,
                              hipStream_t stream)
{
    const float* queries = (const float*)d_in[0];
    const int*   qmask   = (const int*)  d_in[1];
    const float* keys    = (const float*)d_in[2];
    const int*   kmask   = (const int*)  d_in[3];
    const float* Wq      = (const float*)d_in[4];
    const float* bq      = (const float*)d_in[5];
    const float* Wk      = (const float*)d_in[6];
    const float* bk      = (const float*)d_in[7];
    const float* Wv      = (const float*)d_in[8];
    const float* bv      = (const float*)d_in[9];
    const float* gamma   = (const float*)d_in[10];
    const float* beta    = (const float*)d_in[11];
    float* out = (float*)d_out;

    unsigned short* Xqb = (unsigned short*)d_ws;
    unsigned short* Xkb = Xqb + (size_t)B_*T_*H_;
    unsigned short* Wqb = Xkb + (size_t)B_*S_*H_;
    unsigned short* Wkb = Wqb + (size_t)H_*H_;
    unsigned short* Wvb = Wkb + (size_t)H_*H_;
    unsigned short* Qb  = Wvb + (size_t)H_*H_;
    unsigned short* Kb  = Qb  + (size_t)B_*T_*H_;
    unsigned short* Vb  = Kb  + (size_t)B_*S_*H_;
    float* vmeanF = (float*)Xqb;          // dead-after-GEMM region (Xqb)
    int*   sfirstI = (int*)(vmeanF + 256*64);
    unsigned short* Ob = Xkb;             // dead-after-GEMM region (Xkb), 8 MB

    dim3 gc((B_*T_*H_/8 + 255)/256, 5, 1);
    cast_bf16<<<gc, 256, 0, stream>>>(queries, keys, Wq, Wk, Wv,
                                      Xqb, Xkb, Wqb, Wkb, Wvb);

    qkv_mfma<<<768, 512, 0, stream>>>(Xqb, Xkb, Wqb, Wkb, Wvb,
                                      bq, bk, bv, Qb, Kb, Vb);

    vmean_prep<<<256, 256, 0, stream>>>(Vb, kmask, vmeanF, sfirstI);

    attn_mfma<<<1024, 256, 0, stream>>>(Qb, Kb, Vb, kmask, vmeanF, sfirstI, Ob);

    ln_kernel<<<B_*T_, 256, 0, stream>>>(Ob, out, queries, qmask, gamma, beta);
}